// Round 6
// baseline (4084.712 us; speedup 1.0000x reference)
//
#include <hip/hip_runtime.h>
#include <hip/hip_bf16.h>
#include <cstdint>
#include <cstddef>

#define NTOK 2048
#define HID  2048
#define NINT 5632
#define NEXP 8

typedef __attribute__((ext_vector_type(8))) short short8;
typedef __attribute__((ext_vector_type(4))) float f32x4;
typedef __attribute__((ext_vector_type(4))) float fl4;

__device__ __forceinline__ unsigned short f2bf(float f) {
    union { float f; unsigned int u; } v; v.f = f;
    unsigned int r = (v.u + 0x7fffu + ((v.u >> 16) & 1u)) >> 16;
    return (unsigned short)r;
}

// pack 2 floats -> 2 bf16 (v_cvt_pk_bf16_f32, RNE)
__device__ __forceinline__ unsigned int pk2(float x, float y) {
    __hip_bfloat162 h = __float22bfloat162_rn(make_float2(x, y));
    union { __hip_bfloat162 h; unsigned int u; } c; c.h = h;
    return c.u;
}

// async global->LDS DMA, 16 B per lane: lane l's gsrc -> lds_base + l*16
__device__ __forceinline__ void gload16(const void* g, void* l) {
    __builtin_amdgcn_global_load_lds(
        (const __attribute__((address_space(1))) unsigned int*)g,
        (__attribute__((address_space(3))) unsigned int*)l, 16, 0, 0);
}

#define WAITV2() asm volatile("s_waitcnt vmcnt(2)" ::: "memory")
#define WAITV0() asm volatile("s_waitcnt vmcnt(0)" ::: "memory")
#define WAITL0() asm volatile("s_waitcnt lgkmcnt(0)" ::: "memory")
#define BAR()    __builtin_amdgcn_s_barrier()
#define SCH()    __builtin_amdgcn_sched_barrier(0)

// meta layout (ints): [0..7]=cnt, [8..15]=cursor, [16..24]=offs
__global__ void zero_kernel(float* __restrict__ out, int* __restrict__ meta) {
    int idx = blockIdx.x * blockDim.x + threadIdx.x;
    fl4 z = {0.f, 0.f, 0.f, 0.f};
    ((fl4*)out)[idx] = z;
    if (blockIdx.x == 0 && threadIdx.x < 16) meta[threadIdx.x] = 0;
}

__device__ __forceinline__ void top2_route(const float* __restrict__ lg, int t,
                                           int& e0, int& e1, float& w0, float& w1) {
    float l[NEXP];
#pragma unroll
    for (int e = 0; e < NEXP; ++e) l[e] = lg[t * NEXP + e];
    e0 = 0; float b0l = l[0];
#pragma unroll
    for (int e = 1; e < NEXP; ++e) if (l[e] > b0l) { b0l = l[e]; e0 = e; }
    e1 = (e0 == 0) ? 1 : 0; float b1l = l[e1];
#pragma unroll
    for (int e = 0; e < NEXP; ++e) {
        if (e == e0) continue;
        if (l[e] > b1l) { b1l = l[e]; e1 = e; }
    }
    float m = b0l;
    float p0 = __expf(b0l - m), p1 = __expf(b1l - m);
    float inv = 1.f / (p0 + p1);
    w0 = p0 * inv; w1 = p1 * inv;
}

__global__ void route_count(const float* __restrict__ logits, int* __restrict__ meta) {
    int t = blockIdx.x * blockDim.x + threadIdx.x;
    int e0, e1; float w0, w1;
    top2_route(logits, t, e0, e1, w0, w1);
    atomicAdd(&meta[e0], 1);
    atomicAdd(&meta[e1], 1);
}

__global__ void scan_kernel(int* __restrict__ meta) {
    if (threadIdx.x == 0 && blockIdx.x == 0) {
        int s = 0;
#pragma unroll
        for (int e = 0; e < NEXP; ++e) { meta[16 + e] = s; s += meta[e]; }
        meta[16 + NEXP] = s;
    }
}

__global__ void route_assign(const float* __restrict__ logits, int* __restrict__ meta,
                             int* __restrict__ rowTok, float* __restrict__ rowW) {
    int t = blockIdx.x * blockDim.x + threadIdx.x;
    int e0, e1; float w0, w1;
    top2_route(logits, t, e0, e1, w0, w1);
    int p0 = atomicAdd(&meta[8 + e0], 1);
    int s0 = meta[16 + e0] + p0;
    rowTok[s0] = t; rowW[s0] = w0;
    int p1 = atomicAdd(&meta[8 + e1], 1);
    int s1 = meta[16 + e1] + p1;
    rowTok[s1] = t; rowW[s1] = w1;
}

__global__ void gather_x(const float* __restrict__ x, const int* __restrict__ rowTok,
                         unsigned short* __restrict__ xg) {
    int slot = blockIdx.x;
    int tok = rowTok[slot];
    int c = threadIdx.x;
    const fl4* src = (const fl4*)(x + (size_t)tok * HID);
    fl4 a = src[c * 2], b = src[c * 2 + 1];
    short8 v;
    v[0] = (short)f2bf(a[0]); v[1] = (short)f2bf(a[1]); v[2] = (short)f2bf(a[2]); v[3] = (short)f2bf(a[3]);
    v[4] = (short)f2bf(b[0]); v[5] = (short)f2bf(b[1]); v[6] = (short)f2bf(b[2]); v[7] = (short)f2bf(b[3]);
    *(short8*)(xg + (size_t)slot * HID + c * 8) = v;
}

// ---------------- GEMM1 ----------------
// 1024 thr (16 waves). Tile: 256 token-rows x (64 gate + 64 up) B-rows, BK=32.
// A (xg bf16) + Braw (fp32 weights) stream via global_load_lds 2-stage rings,
// counted vmcnt (never drained). cvt fp32->bf16 LDS->LDS per step.
__global__ __launch_bounds__(1024, 4) void gemm1_kernel(
        const unsigned short* __restrict__ xg,
        const float* __restrict__ w1, const float* __restrict__ w3,
        const int* __restrict__ meta, unsigned short* __restrict__ act) {
    const int ch = blockIdx.x;      // 16 chunks of 256 rows
    const int it = blockIdx.y;      // 88 tiles of 64 inter cols
    const int e  = blockIdx.z;      // 8 experts
    const int r0 = meta[16 + e];
    const int Ne = meta[17 + e] - r0;
    const int cb = ch * 256;
    if (cb >= Ne) return;

    __shared__ __align__(16) short As[2][256][32];    // 32 KB (bf16, swizzled k-slots)
    __shared__ __align__(16) float Braw[2][128][32];  // 32 KB (fp32, linear)
    __shared__ __align__(16) short Bbf[128][40];      // 10 KB (bf16, padded)

    const int tid = threadIdx.x;
    const int wv = tid >> 6, l = tid & 63;
    const int cl = l & 15, kq = l >> 4;

    // A staging: thread covers stage row sra (0..255), 8-elem slot sa (0..3).
    // Pre-swizzled global source: LDS slot s holds global k-slot s ^ ((row>>1)&3).
    const int sra = tid >> 2, sa = tid & 3;
    int grow = cb + sra; if (grow > Ne - 1) grow = Ne - 1;
    const unsigned short* agp = xg + (size_t)(r0 + grow) * HID + (sa ^ ((sra >> 1) & 3)) * 8;
    // B staging: stage row srb (0..127 = 64 gate + 64 up), 4-float slot sb (0..7)
    const int srb = tid >> 3, sb = tid & 7;
    const float* bgp = (srb < 64)
        ? (w1 + ((size_t)e * NINT + (size_t)it * 64 + srb) * HID + sb * 4)
        : (w3 + ((size_t)e * NINT + (size_t)it * 64 + (srb - 64)) * HID + sb * 4);
    char* aLb = (char*)&As[0][wv * 16][0];     // wave-uniform DMA bases (+ lane*16 by HW)
    char* bLb = (char*)&Braw[0][wv * 8][0];

    // cvt coords: byte tid*16 of Braw stage (linear, conflict-free)
    const int crow = tid >> 3, cs = tid & 7;
    const char* cvR = (const char*)&Braw[0][crow][cs * 4];
    short* cvW = &Bbf[crow][cs * 4];

    // mfma A-read coords (wave-private rows wv*16..+15)
    const char* aRd = (const char*)&As[0][wv * 16 + cl][(kq ^ ((cl >> 1) & 3)) * 8];

    f32x4 acc[8];
#pragma unroll
    for (int f = 0; f < 8; ++f) acc[f] = (f32x4){0.f, 0.f, 0.f, 0.f};

    const int NS = HID / 32;   // 64
    // prologue: stages 0 and 1 in flight (2 ops/wave each)
    gload16(agp,      aLb);
    gload16(bgp,      bLb);
    gload16(agp + 32, aLb + 16384);
    gload16(bgp + 32, bLb + 16384);
    SCH();

#pragma unroll 1
    for (int i = 0; i < NS; ++i) {
        if (i < NS - 2) { WAITV2(); } else { WAITV0(); }   // own stage i landed
        SCH();
        const int so = (i & 1) * 16384;
        {   // CVT(i): own Braw rows -> own Bbf rows
            fl4 c = *(const fl4*)(cvR + so);
            unsigned long long uu = ((unsigned long long)pk2(c[2], c[3]) << 32) | pk2(c[0], c[1]);
            *(unsigned long long*)cvW = uu;
        }
        WAITL0(); BAR(); SCH();      // Bbf(i) visible to all waves
        {   // MFMA(i)
            short8 af = *(const short8*)(aRd + so);
#pragma unroll
            for (int f = 0; f < 8; ++f) {
                short8 bfm = *(const short8*)&Bbf[f * 16 + cl][kq * 8];
                acc[f] = __builtin_amdgcn_mfma_f32_16x16x32_bf16(af, bfm, acc[f], 0, 0, 0);
            }
        }
        SCH(); WAITL0(); BAR(); SCH();   // all Bbf reads done; own ring reads done
        if (i + 2 < NS) {                // refill slot just consumed
            const int k0 = (i + 2) * 32;
            gload16(agp + k0, aLb + so);
            gload16(bgp + k0, bLb + so);
        }
    }

    // epilogue: y = silu(gate)*up -> act bf16
#pragma unroll
    for (int f = 0; f < 4; ++f) {
        f32x4 g = acc[f], u = acc[f + 4];
#pragma unroll
        for (int j = 0; j < 4; ++j) {
            int r = cb + wv * 16 + kq * 4 + j;
            if (r < Ne) {
                float gv = g[j];
                float y = gv / (1.f + __expf(-gv)) * u[j];
                act[(size_t)(r0 + r) * NINT + (size_t)it * 64 + f * 16 + cl] = f2bf(y);
            }
        }
    }
}

// ---------------- GEMM2 ----------------
// Same structure: 256 rows x 128 hid-cols, K = NINT.
__global__ __launch_bounds__(1024, 4) void gemm2_kernel(
        const unsigned short* __restrict__ act, const float* __restrict__ w2,
        const int* __restrict__ meta, const int* __restrict__ rowTok,
        const float* __restrict__ rowW, float* __restrict__ out) {
    const int ch = blockIdx.x;      // 16 chunks of 256 rows
    const int ht = blockIdx.y;      // 16 tiles of 128 hid cols
    const int e  = blockIdx.z;
    const int r0 = meta[16 + e];
    const int Ne = meta[17 + e] - r0;
    const int cb = ch * 256;
    if (cb >= Ne) return;

    __shared__ __align__(16) short As[2][256][32];
    __shared__ __align__(16) float Braw[2][128][32];
    __shared__ __align__(16) short Bbf[128][40];

    const int tid = threadIdx.x;
    const int wv = tid >> 6, l = tid & 63;
    const int cl = l & 15, kq = l >> 4;

    const int sra = tid >> 2, sa = tid & 3;
    int grow = cb + sra; if (grow > Ne - 1) grow = Ne - 1;
    const unsigned short* agp = act + (size_t)(r0 + grow) * NINT + (sa ^ ((sra >> 1) & 3)) * 8;
    const int srb = tid >> 3, sb = tid & 7;
    const float* bgp = w2 + ((size_t)e * HID + (size_t)ht * 128 + srb) * NINT + sb * 4;
    char* aLb = (char*)&As[0][wv * 16][0];
    char* bLb = (char*)&Braw[0][wv * 8][0];

    const int crow = tid >> 3, cs = tid & 7;
    const char* cvR = (const char*)&Braw[0][crow][cs * 4];
    short* cvW = &Bbf[crow][cs * 4];

    const char* aRd = (const char*)&As[0][wv * 16 + cl][(kq ^ ((cl >> 1) & 3)) * 8];

    f32x4 acc[8];
#pragma unroll
    for (int f = 0; f < 8; ++f) acc[f] = (f32x4){0.f, 0.f, 0.f, 0.f};

    const int NS = NINT / 32;   // 176
    gload16(agp,      aLb);
    gload16(bgp,      bLb);
    gload16(agp + 32, aLb + 16384);
    gload16(bgp + 32, bLb + 16384);
    SCH();

#pragma unroll 1
    for (int i = 0; i < NS; ++i) {
        if (i < NS - 2) { WAITV2(); } else { WAITV0(); }
        SCH();
        const int so = (i & 1) * 16384;
        {
            fl4 c = *(const fl4*)(cvR + so);
            unsigned long long uu = ((unsigned long long)pk2(c[2], c[3]) << 32) | pk2(c[0], c[1]);
            *(unsigned long long*)cvW = uu;
        }
        WAITL0(); BAR(); SCH();
        {
            short8 af = *(const short8*)(aRd + so);
#pragma unroll
            for (int f = 0; f < 8; ++f) {
                short8 bfm = *(const short8*)&Bbf[f * 16 + cl][kq * 8];
                acc[f] = __builtin_amdgcn_mfma_f32_16x16x32_bf16(af, bfm, acc[f], 0, 0, 0);
            }
        }
        SCH(); WAITL0(); BAR(); SCH();
        if (i + 2 < NS) {
            const int k0 = (i + 2) * 32;
            gload16(agp + k0, aLb + so);
            gload16(bgp + k0, bLb + so);
        }
    }

#pragma unroll
    for (int j = 0; j < 4; ++j) {
        int r = cb + wv * 16 + kq * 4 + j;
        if (r < Ne) {
            int slot = r0 + r;
            int tok = rowTok[slot];
            float sw = rowW[slot];
#pragma unroll
            for (int f = 0; f < 8; ++f)
                atomicAdd(&out[(size_t)tok * HID + (size_t)ht * 128 + f * 16 + cl], acc[f][j] * sw);
        }
    }
}

extern "C" void kernel_launch(void* const* d_in, const int* in_sizes, int n_in,
                              void* d_out, int out_size, void* d_ws, size_t ws_size,
                              hipStream_t stream) {
    const float* x      = (const float*)d_in[0];
    const float* logits = (const float*)d_in[1];
    const float* w1     = (const float*)d_in[2];
    const float* w3     = (const float*)d_in[3];
    const float* w2     = (const float*)d_in[4];
    float* out = (float*)d_out;

    char* ws = (char*)d_ws;
    int*   meta   = (int*)ws;                       // 32 ints
    int*   rowTok = (int*)(ws + 512);               // 4096 ints
    float* rowW   = (float*)(ws + 512 + 16384);     // 4096 floats
    unsigned short* xg  = (unsigned short*)(ws + (1u << 20));   // 16 MB
    unsigned short* act = (unsigned short*)(ws + (18u << 20));  // 44 MB

    zero_kernel<<<4096, 256, 0, stream>>>(out, meta);
    route_count<<<8, 256, 0, stream>>>(logits, meta);
    scan_kernel<<<1, 1, 0, stream>>>(meta);
    route_assign<<<8, 256, 0, stream>>>(logits, meta, rowTok, rowW);
    gather_x<<<4096, 256, 0, stream>>>(x, rowTok, xg);
    gemm1_kernel<<<dim3(16, 88, 8), 1024, 0, stream>>>(xg, w1, w3, meta, act);
    gemm2_kernel<<<dim3(16, 16, 8), 1024, 0, stream>>>(act, w2, meta, rowTok, rowW, out);
}

// Round 7
// 1598.835 us; speedup vs baseline: 2.5548x; 2.5548x over previous
//
#include <hip/hip_runtime.h>
#include <hip/hip_bf16.h>
#include <cstdint>
#include <cstddef>

#define NTOK 2048
#define HID  2048
#define NINT 5632
#define NEXP 8

typedef __attribute__((ext_vector_type(8))) short short8;
typedef __attribute__((ext_vector_type(4))) float f32x4;
typedef __attribute__((ext_vector_type(4))) float fl4;

__device__ __forceinline__ unsigned short f2bf(float f) {
    union { float f; unsigned int u; } v; v.f = f;
    unsigned int r = (v.u + 0x7fffu + ((v.u >> 16) & 1u)) >> 16;
    return (unsigned short)r;
}

// pack 2 floats -> 2 bf16 (v_cvt_pk_bf16_f32, RNE)
__device__ __forceinline__ unsigned int pk2(float x, float y) {
    __hip_bfloat162 h = __float22bfloat162_rn(make_float2(x, y));
    union { __hip_bfloat162 h; unsigned int u; } c; c.h = h;
    return c.u;
}

// async global->LDS DMA, 16 B per lane: lane l reads gsrc(l) -> ldsbase + l*16
__device__ __forceinline__ void gload16(const void* g, void* l) {
    __builtin_amdgcn_global_load_lds(
        (const __attribute__((address_space(1))) unsigned int*)g,
        (__attribute__((address_space(3))) unsigned int*)l, 16, 0, 0);
}

#define WAITV8() asm volatile("s_waitcnt vmcnt(8)" ::: "memory")
#define WAITV0() asm volatile("s_waitcnt vmcnt(0)" ::: "memory")
#define BAR()    __builtin_amdgcn_s_barrier()
#define SCH()    __builtin_amdgcn_sched_barrier(0)

// meta layout (ints): [0..7]=cnt, [8..15]=cursor, [16..24]=offs
__global__ void zero_kernel(float* __restrict__ out, int* __restrict__ meta) {
    int idx = blockIdx.x * blockDim.x + threadIdx.x;
    fl4 z = {0.f, 0.f, 0.f, 0.f};
    ((fl4*)out)[idx] = z;
    if (blockIdx.x == 0 && threadIdx.x < 16) meta[threadIdx.x] = 0;
}

__device__ __forceinline__ void top2_route(const float* __restrict__ lg, int t,
                                           int& e0, int& e1, float& w0, float& w1) {
    float l[NEXP];
#pragma unroll
    for (int e = 0; e < NEXP; ++e) l[e] = lg[t * NEXP + e];
    e0 = 0; float b0l = l[0];
#pragma unroll
    for (int e = 1; e < NEXP; ++e) if (l[e] > b0l) { b0l = l[e]; e0 = e; }
    e1 = (e0 == 0) ? 1 : 0; float b1l = l[e1];
#pragma unroll
    for (int e = 0; e < NEXP; ++e) {
        if (e == e0) continue;
        if (l[e] > b1l) { b1l = l[e]; e1 = e; }
    }
    float m = b0l;
    float p0 = __expf(b0l - m), p1 = __expf(b1l - m);
    float inv = 1.f / (p0 + p1);
    w0 = p0 * inv; w1 = p1 * inv;
}

__global__ void route_count(const float* __restrict__ logits, int* __restrict__ meta) {
    int t = blockIdx.x * blockDim.x + threadIdx.x;
    int e0, e1; float w0, w1;
    top2_route(logits, t, e0, e1, w0, w1);
    atomicAdd(&meta[e0], 1);
    atomicAdd(&meta[e1], 1);
}

__global__ void scan_kernel(int* __restrict__ meta) {
    if (threadIdx.x == 0 && blockIdx.x == 0) {
        int s = 0;
#pragma unroll
        for (int e = 0; e < NEXP; ++e) { meta[16 + e] = s; s += meta[e]; }
        meta[16 + NEXP] = s;
    }
}

__global__ void route_assign(const float* __restrict__ logits, int* __restrict__ meta,
                             int* __restrict__ rowTok, float* __restrict__ rowW) {
    int t = blockIdx.x * blockDim.x + threadIdx.x;
    int e0, e1; float w0, w1;
    top2_route(logits, t, e0, e1, w0, w1);
    int p0 = atomicAdd(&meta[8 + e0], 1);
    int s0 = meta[16 + e0] + p0;
    rowTok[s0] = t; rowW[s0] = w0;
    int p1 = atomicAdd(&meta[8 + e1], 1);
    int s1 = meta[16 + e1] + p1;
    rowTok[s1] = t; rowW[s1] = w1;
}

__global__ void gather_x(const float* __restrict__ x, const int* __restrict__ rowTok,
                         unsigned short* __restrict__ xg) {
    int slot = blockIdx.x;
    int tok = rowTok[slot];
    int c = threadIdx.x;
    const fl4* src = (const fl4*)(x + (size_t)tok * HID);
    fl4 a = src[c * 2], b = src[c * 2 + 1];
    short8 v;
    v[0] = (short)f2bf(a[0]); v[1] = (short)f2bf(a[1]); v[2] = (short)f2bf(a[2]); v[3] = (short)f2bf(a[3]);
    v[4] = (short)f2bf(b[0]); v[5] = (short)f2bf(b[1]); v[6] = (short)f2bf(b[2]); v[7] = (short)f2bf(b[3]);
    *(short8*)(xg + (size_t)slot * HID + c * 8) = v;
}

// ======================= GEMM CORE (shared pattern) =======================
// Block: 512 thr (8 waves, 4 row-groups x 2 col-groups). Tile: 256 A-rows x
// (2x16) B-cols per wave. BK=64. A (bf16): global_load_lds double buffer,
// source pre-swizzled (slot ^= row&7) so ds_read_b128 is conflict-free.
// B (fp32 weights): per-wave-exclusive cols, global->VGPR->cvt_pk->MFMA.
// One raw s_barrier per step; counted vmcnt only (never a full drain):
//   step k: vmcnt(0)[=own 8 B(k)] -> cvt -> issue DMA(k+1)+B(k+1)
//           -> 16 MFMA -> vmcnt(8)[=own 4 DMA(k+1)] -> s_barrier
// Per-wave symmetric waits make the barrier sufficient for DMA visibility.

// A-DMA: 4 calls/thread; call j: wave wv covers rows (wv*4+j)*8 + (l>>3),
// slot l&7, i.e. LDS linear = base + lane*16 with row stride 128B.

#define GEMM_PIPE(APTR_EXPR, LDK, NS)                                            \
    const int tid = threadIdx.x;                                                 \
    const int wv = tid >> 6, l = tid & 63;                                       \
    const int cl = l & 15, kq = l >> 4;                                          \
    const int wr = wv >> 1, wc = wv & 1;                                         \
    const unsigned short* asrc[4];                                               \
    _Pragma("unroll") for (int j = 0; j < 4; ++j) {                              \
        int rrow = cb + (wv * 4 + j) * 8 + (l >> 3);                             \
        if (rrow > Ne - 1) rrow = Ne - 1;                                        \
        asrc[j] = (APTR_EXPR) + (size_t)(r0 + rrow) * (LDK)                      \
                  + (((l & 7) ^ ((l >> 3) & 7)) << 3);                           \
    }                                                                            \
    f32x4 acc[4][2];                                                             \
    _Pragma("unroll") for (int rf = 0; rf < 4; ++rf) {                           \
        acc[rf][0] = (f32x4){0.f, 0.f, 0.f, 0.f};                                \
        acc[rf][1] = (f32x4){0.f, 0.f, 0.f, 0.f};                                \
    }                                                                            \
    fl4 b0[4], b1[4];                                                            \
    short8 f0[2], f1[2];

#define ISSUE_A(K, BUF) do {                                                     \
        char* base_ = (char*)As + (BUF) * 32768 + wv * 4096;                     \
        gload16(asrc[0] + (K), base_);                                           \
        gload16(asrc[1] + (K), base_ + 1024);                                    \
        gload16(asrc[2] + (K), base_ + 2048);                                    \
        gload16(asrc[3] + (K), base_ + 3072);                                    \
    } while (0)

#define ISSUE_B(K) do {                                                          \
        _Pragma("unroll") for (int j = 0; j < 4; ++j) {                          \
            int off_ = (K) + ((j & 1) << 2) + ((j >> 1) << 5);                   \
            b0[j] = *(const fl4*)(p0 + off_);                                    \
            b1[j] = *(const fl4*)(p1 + off_);                                    \
        }                                                                        \
    } while (0)

#define CVT_B() do {                                                             \
        union { short8 s; unsigned int u[4]; } t0_, t1_, t2_, t3_;               \
        t0_.u[0] = pk2(b0[0][0], b0[0][1]); t0_.u[1] = pk2(b0[0][2], b0[0][3]);  \
        t0_.u[2] = pk2(b0[1][0], b0[1][1]); t0_.u[3] = pk2(b0[1][2], b0[1][3]);  \
        t1_.u[0] = pk2(b0[2][0], b0[2][1]); t1_.u[1] = pk2(b0[2][2], b0[2][3]);  \
        t1_.u[2] = pk2(b0[3][0], b0[3][1]); t1_.u[3] = pk2(b0[3][2], b0[3][3]);  \
        t2_.u[0] = pk2(b1[0][0], b1[0][1]); t2_.u[1] = pk2(b1[0][2], b1[0][3]);  \
        t2_.u[2] = pk2(b1[1][0], b1[1][1]); t2_.u[3] = pk2(b1[1][2], b1[1][3]);  \
        t3_.u[0] = pk2(b1[2][0], b1[2][1]); t3_.u[1] = pk2(b1[2][2], b1[2][3]);  \
        t3_.u[2] = pk2(b1[3][0], b1[3][1]); t3_.u[3] = pk2(b1[3][2], b1[3][3]);  \
        f0[0] = t0_.s; f0[1] = t1_.s; f1[0] = t2_.s; f1[1] = t3_.s;              \
    } while (0)

#define COMPUTE(BUF) do {                                                        \
        _Pragma("unroll") for (int kk = 0; kk < 2; ++kk) {                       \
            _Pragma("unroll") for (int rf = 0; rf < 4; ++rf) {                   \
                int row_ = wr * 64 + rf * 16 + cl;                               \
                int slot_ = ((kk << 2) + kq) ^ (cl & 7);                         \
                short8 af_ = *(const short8*)((const char*)As + (BUF) * 32768    \
                                              + row_ * 128 + slot_ * 16);        \
                acc[rf][0] = __builtin_amdgcn_mfma_f32_16x16x32_bf16(af_, f0[kk], acc[rf][0], 0, 0, 0); \
                acc[rf][1] = __builtin_amdgcn_mfma_f32_16x16x32_bf16(af_, f1[kk], acc[rf][1], 0, 0, 0); \
            }                                                                    \
        }                                                                        \
    } while (0)

#define PIPE_LOOP(NS) do {                                                       \
        ISSUE_A(0, 0);                                                           \
        ISSUE_B(0);                                                              \
        SCH(); WAITV8(); BAR(); SCH();                                           \
        _Pragma("unroll 1")                                                      \
        for (int k = 0; k < (NS); ++k) {                                         \
            WAITV0(); SCH();                                                     \
            CVT_B();                                                             \
            SCH();                                                               \
            if (k + 1 < (NS)) {                                                  \
                ISSUE_A((k + 1) * 64, (k + 1) & 1);                              \
                ISSUE_B((k + 1) * 64);                                           \
            }                                                                    \
            SCH();                                                               \
            COMPUTE(k & 1);                                                      \
            SCH();                                                               \
            if (k + 1 < (NS)) { WAITV8(); }                                      \
            BAR(); SCH();                                                        \
        }                                                                        \
    } while (0)

// ---------------- GEMM1: act = silu(xg@w1^T) * (xg@w3^T) ----------------
__global__ __launch_bounds__(512) void gemm1_kernel(
        const unsigned short* __restrict__ xg,
        const float* __restrict__ w1, const float* __restrict__ w3,
        const int* __restrict__ meta, unsigned short* __restrict__ act) {
    const int it = blockIdx.x;      // 176 tiles of 32 inter cols
    const int e  = blockIdx.y;      // 8 experts
    const int ch = blockIdx.z;      // 8 chunks of 256 rows
    const int r0 = meta[16 + e];
    const int Ne = meta[17 + e] - r0;
    const int cb = ch * 256;
    if (cb >= Ne) return;

    __shared__ __align__(16) char As[2 * 32768];    // 64 KB: [2][256 rows][128 B]

    GEMM_PIPE(xg, HID, 32)

    // B cols: gate col = up col = it*32 + wc*16 + cl (gate from w1, up from w3)
    const float* p0 = w1 + ((size_t)e * NINT + it * 32 + wc * 16 + cl) * HID + kq * 8;
    const float* p1 = w3 + ((size_t)e * NINT + it * 32 + wc * 16 + cl) * HID + kq * 8;

    PIPE_LOOP(32);

    // epilogue: y = silu(gate)*up -> act bf16 (C: col=cl, row=kq*4+j)
#pragma unroll
    for (int rf = 0; rf < 4; ++rf) {
#pragma unroll
        for (int j = 0; j < 4; ++j) {
            int r = cb + wr * 64 + rf * 16 + kq * 4 + j;
            if (r < Ne) {
                float gv = acc[rf][0][j];
                float y = gv / (1.f + __expf(-gv)) * acc[rf][1][j];
                act[(size_t)(r0 + r) * NINT + it * 32 + wc * 16 + cl] = f2bf(y);
            }
        }
    }
}

// ---------------- GEMM2: out += rowW * (act @ w2^T) ----------------
__global__ __launch_bounds__(512) void gemm2_kernel(
        const unsigned short* __restrict__ act, const float* __restrict__ w2,
        const int* __restrict__ meta, const int* __restrict__ rowTok,
        const float* __restrict__ rowW, float* __restrict__ out) {
    const int ht = blockIdx.x;      // 32 tiles of 64 hid cols
    const int e  = blockIdx.y;
    const int ch = blockIdx.z;
    const int r0 = meta[16 + e];
    const int Ne = meta[17 + e] - r0;
    const int cb = ch * 256;
    if (cb >= Ne) return;

    __shared__ __align__(16) char As[2 * 32768];

    GEMM_PIPE(act, NINT, 88)

    // B cols: ht*64 + wc*32 + cf*16 + cl  (cf = 0,1)
    const float* p0 = w2 + ((size_t)e * HID + ht * 64 + wc * 32 + cl) * NINT + kq * 8;
    const float* p1 = p0 + (size_t)16 * NINT;

    PIPE_LOOP(88);

#pragma unroll
    for (int rf = 0; rf < 4; ++rf) {
#pragma unroll
        for (int j = 0; j < 4; ++j) {
            int r = cb + wr * 64 + rf * 16 + kq * 4 + j;
            if (r < Ne) {
                int slot = r0 + r;
                int tok = rowTok[slot];
                float sw = rowW[slot];
                atomicAdd(&out[(size_t)tok * HID + ht * 64 + wc * 32 + cl],      acc[rf][0][j] * sw);
                atomicAdd(&out[(size_t)tok * HID + ht * 64 + wc * 32 + 16 + cl], acc[rf][1][j] * sw);
            }
        }
    }
}

extern "C" void kernel_launch(void* const* d_in, const int* in_sizes, int n_in,
                              void* d_out, int out_size, void* d_ws, size_t ws_size,
                              hipStream_t stream) {
    const float* x      = (const float*)d_in[0];
    const float* logits = (const float*)d_in[1];
    const float* w1     = (const float*)d_in[2];
    const float* w3     = (const float*)d_in[3];
    const float* w2     = (const float*)d_in[4];
    float* out = (float*)d_out;

    char* ws = (char*)d_ws;
    int*   meta   = (int*)ws;                       // 32 ints
    int*   rowTok = (int*)(ws + 512);               // 4096 ints
    float* rowW   = (float*)(ws + 512 + 16384);     // 4096 floats
    unsigned short* xg  = (unsigned short*)(ws + (1u << 20));   // 16 MB
    unsigned short* act = (unsigned short*)(ws + (18u << 20));  // 44 MB

    zero_kernel<<<4096, 256, 0, stream>>>(out, meta);
    route_count<<<8, 256, 0, stream>>>(logits, meta);
    scan_kernel<<<1, 1, 0, stream>>>(meta);
    route_assign<<<8, 256, 0, stream>>>(logits, meta, rowTok, rowW);
    gather_x<<<4096, 256, 0, stream>>>(x, rowTok, xg);
    gemm1_kernel<<<dim3(176, 8, 8), 512, 0, stream>>>(xg, w1, w3, meta, act);
    gemm2_kernel<<<dim3(32, 8, 8), 512, 0, stream>>>(act, w2, meta, rowTok, rowW, out);
}